// Round 10
// baseline (385.673 us; speedup 1.0000x reference)
//
#include <hip/hip_runtime.h>
#include <hip/hip_bf16.h>
#include <math.h>

#define B_ 2
#define T_ 2048
#define C_ 1024
#define H_ 16
#define HS_ 64
#define N_ROWS (B_*T_)   // 4096
#define MB (1024*1024)

typedef __attribute__((ext_vector_type(8))) short bf16x8;
typedef __attribute__((ext_vector_type(8))) unsigned short u16x8;
typedef __attribute__((ext_vector_type(4))) float floatx4;

static __device__ __forceinline__ unsigned short f2bf(float f) {
  union { float f; unsigned u; } v; v.f = f;
  unsigned r = v.u + 0x7fff + ((v.u >> 16) & 1);   // round-to-nearest-even
  return (unsigned short)(r >> 16);
}
static __device__ __forceinline__ float bf2f(unsigned short s) {
  union { unsigned u; float f; } v; v.u = ((unsigned)s) << 16;
  return v.f;
}

// ---------------- LayerNorm: one block per row, bf16 output ----------------
__global__ __launch_bounds__(256) void ln_kernel(
    const float* __restrict__ x, const float* __restrict__ g,
    const float* __restrict__ b, unsigned short* __restrict__ outb)
{
  const int row = blockIdx.x;
  const int tid = threadIdx.x;
  const float* xr = x + (size_t)row * C_;
  float4 xv = *reinterpret_cast<const float4*>(xr + tid * 4);
  float s  = xv.x + xv.y + xv.z + xv.w;
  float ss = xv.x*xv.x + xv.y*xv.y + xv.z*xv.z + xv.w*xv.w;
  #pragma unroll
  for (int off = 32; off > 0; off >>= 1) {
    s  += __shfl_down(s, off, 64);
    ss += __shfl_down(ss, off, 64);
  }
  __shared__ float rs[4], rss[4];
  __shared__ float smu, srstd;
  if ((tid & 63) == 0) { rs[tid >> 6] = s; rss[tid >> 6] = ss; }
  __syncthreads();
  if (tid == 0) {
    float S  = rs[0] + rs[1] + rs[2] + rs[3];
    float SS = rss[0] + rss[1] + rss[2] + rss[3];
    float mu  = S * (1.0f / C_);
    float var = SS * (1.0f / C_) - mu * mu;
    smu = mu; srstd = rsqrtf(var + 1e-5f);
  }
  __syncthreads();
  const float mu = smu, rstd = srstd;
  float4 gv = *reinterpret_cast<const float4*>(g + tid * 4);
  float4 bv = *reinterpret_cast<const float4*>(b + tid * 4);
  union { unsigned long long ll; unsigned short s[4]; } o;
  o.s[0] = f2bf((xv.x - mu) * rstd * gv.x + bv.x);
  o.s[1] = f2bf((xv.y - mu) * rstd * gv.y + bv.y);
  o.s[2] = f2bf((xv.z - mu) * rstd * gv.z + bv.z);
  o.s[3] = f2bf((xv.w - mu) * rstd * gv.w + bv.w);
  *reinterpret_cast<unsigned long long*>(outb + (size_t)row * C_ + tid * 4) = o.ll;
}

// ---------------- Transpose + cast: fp32 [R][Cc] -> bf16 [Cc][R], batched ---
__global__ __launch_bounds__(256) void transpose_cast(
    const float* __restrict__ in, unsigned short* __restrict__ out, int R, int Cc)
{
  __shared__ float tile[32][33];
  const int bz = blockIdx.z;
  in  += (size_t)bz * R * Cc;
  out += (size_t)bz * R * Cc;
  const int tx = threadIdx.x & 31;
  const int ty = threadIdx.x >> 5;    // 0..7
  const int c0 = blockIdx.x * 32, r0 = blockIdx.y * 32;
  #pragma unroll
  for (int j = 0; j < 4; ++j)
    tile[ty + j*8][tx] = in[(size_t)(r0 + ty + j*8) * Cc + c0 + tx];
  __syncthreads();
  #pragma unroll
  for (int j = 0; j < 4; ++j)
    out[(size_t)(c0 + ty + j*8) * R + r0 + tx] = f2bf(tile[tx][ty + j*8]);
}

// Fused QKV weight transpose: z in [0,48) -> which = z/16, head = z%16.
__global__ __launch_bounds__(256) void transpose_cast_qkv(
    const float* __restrict__ Wq, const float* __restrict__ Wk,
    const float* __restrict__ Wv, unsigned short* __restrict__ out)
{
  __shared__ float tile[32][33];
  const int z = blockIdx.z;
  const int which = z >> 4, h = z & 15;
  const float* in = (which == 0 ? Wq : which == 1 ? Wk : Wv) + (size_t)h * C_ * HS_;
  unsigned short* dst = out + (size_t)z * C_ * HS_;
  const int tx = threadIdx.x & 31;
  const int ty = threadIdx.x >> 5;
  const int c0 = blockIdx.x * 32, r0 = blockIdx.y * 32;
  #pragma unroll
  for (int j = 0; j < 4; ++j)
    tile[ty + j*8][tx] = in[(size_t)(r0 + ty + j*8) * HS_ + c0 + tx];
  __syncthreads();
  #pragma unroll
  for (int j = 0; j < 4; ++j)
    dst[(size_t)(c0 + ty + j*8) * C_ + r0 + tx] = f2bf(tile[tx][ty + j*8]);
}

// ---------------- bf16 MFMA GEMM (m97 structure) ----------------
// TNB = 128: 4 waves 2x2, wave-tile 64x64 (acc 4x4). Grid-starved shapes use
// TNB = 64: 4 waves 2x2, wave-tile 64x32 (acc 4x2) -> 2x the block count.
template<int TNB, bool OUTBF16, bool RELU, bool HASB, bool HASRES>
__global__ __launch_bounds__(256) void gemm_bf16(
    const unsigned short* __restrict__ A,   // [M][K] bf16
    const unsigned short* __restrict__ Bt,  // [N][K] bf16
    const float* __restrict__ bias,         // [N] fp32
    const unsigned short* __restrict__ res, // [M][N] bf16
    void* __restrict__ Cout,                // [M][N] fp32 or bf16
    int M, int N, int K)
{
  constexpr int NT = TNB / 32;              // B-tiles per wave: 4 or 2
  constexpr int WN = TNB / 2;               // wave n-extent: 64 or 32
  __shared__ unsigned short As[128 * 32];
  __shared__ unsigned short Bs[TNB * 32];
  const int tid  = threadIdx.x;
  const int lane = tid & 63;
  const int wave = tid >> 6;
  const int wm = wave & 1, wn = wave >> 1;
  const int m0 = blockIdx.x * 128, n0 = blockIdx.y * TNB;

  const int lrow = lane >> 2;
  const int lcol = (lane & 3) * 8;
  const int fr = lane & 15;
  const int fq = lane >> 4;

  floatx4 acc[4][NT] = {};

  const unsigned short* Aw = A  + (size_t)m0 * K;
  const unsigned short* Bw = Bt + (size_t)n0 * K;

  for (int k0 = 0; k0 < K; k0 += 32) {
    __syncthreads();
    #pragma unroll
    for (int i = 0; i < 2; ++i) {
      const int rbase = i * 64 + wave * 16;
      const unsigned short* gp = Aw + (size_t)(rbase + lrow) * K + k0 + lcol;
      __builtin_amdgcn_global_load_lds(
          (const __attribute__((address_space(1))) void*)gp,
          (__attribute__((address_space(3))) void*)(As + rbase * 32),
          16, 0, 0);
    }
    #pragma unroll
    for (int i = 0; i < TNB / 64; ++i) {
      const int rbase = i * 64 + wave * 16;
      const unsigned short* gp = Bw + (size_t)(rbase + lrow) * K + k0 + lcol;
      __builtin_amdgcn_global_load_lds(
          (const __attribute__((address_space(1))) void*)gp,
          (__attribute__((address_space(3))) void*)(Bs + rbase * 32),
          16, 0, 0);
    }
    __syncthreads();

    bf16x8 af[4], bfr[NT];
    #pragma unroll
    for (int t = 0; t < 4; ++t)
      af[t]  = *reinterpret_cast<const bf16x8*>(As + (wm*64 + t*16 + fr)*32 + fq*8);
    #pragma unroll
    for (int t = 0; t < NT; ++t)
      bfr[t] = *reinterpret_cast<const bf16x8*>(Bs + (wn*WN + t*16 + fr)*32 + fq*8);
    #pragma unroll
    for (int mt = 0; mt < 4; ++mt)
      #pragma unroll
      for (int nt = 0; nt < NT; ++nt)
        acc[mt][nt] = __builtin_amdgcn_mfma_f32_16x16x32_bf16(
            af[mt], bfr[nt], acc[mt][nt], 0, 0, 0);
  }

  #pragma unroll
  for (int nt = 0; nt < NT; ++nt) {
    const int col = n0 + wn*WN + nt*16 + fr;
    const float bv = HASB ? bias[col] : 0.0f;
    #pragma unroll
    for (int mt = 0; mt < 4; ++mt) {
      #pragma unroll
      for (int r = 0; r < 4; ++r) {
        const int row = m0 + wm*64 + mt*16 + fq*4 + r;
        float v = acc[mt][nt][r] + bv;
        if (RELU) v = v > 0.0f ? v : 0.0f;
        if (HASRES) v += bf2f(res[(size_t)row * N + col]);
        if (OUTBF16) ((unsigned short*)Cout)[(size_t)row * N + col] = f2bf(v);
        else         ((float*)Cout)[(size_t)row * N + col] = v;
      }
    }
  }
}

// ---------------- split-K (SPLITS-way) bf16 GEMM -> bf16 partials ----------
// blockIdx.z selects the K-slice; partial z at Cpart + z*M*N (contiguous).
template<int TNB, int SPLITS>
__global__ __launch_bounds__(256) void gemm_splitk(
    const unsigned short* __restrict__ A,   // [M][Kfull]
    const unsigned short* __restrict__ Bt,  // [N][Kfull]
    unsigned short* __restrict__ Cpart,     // [SPLITS][M][N] bf16
    int M, int N, int Kfull)
{
  constexpr int NT = TNB / 32;
  constexpr int WN = TNB / 2;
  __shared__ unsigned short As[128 * 32];
  __shared__ unsigned short Bs[TNB * 32];
  const int tid  = threadIdx.x;
  const int lane = tid & 63;
  const int wave = tid >> 6;
  const int wm = wave & 1, wn = wave >> 1;
  const int m0 = blockIdx.x * 128, n0 = blockIdx.y * TNB;
  const int z  = blockIdx.z;
  const int Kh = Kfull / SPLITS;

  const int lrow = lane >> 2;
  const int lcol = (lane & 3) * 8;
  const int fr = lane & 15;
  const int fq = lane >> 4;

  floatx4 acc[4][NT] = {};

  const unsigned short* Aw = A  + (size_t)m0 * Kfull + (size_t)z * Kh;
  const unsigned short* Bw = Bt + (size_t)n0 * Kfull + (size_t)z * Kh;
  unsigned short* Cw = Cpart + (size_t)z * M * N;

  for (int k0 = 0; k0 < Kh; k0 += 32) {
    __syncthreads();
    #pragma unroll
    for (int i = 0; i < 2; ++i) {
      const int rbase = i * 64 + wave * 16;
      const unsigned short* gp = Aw + (size_t)(rbase + lrow) * Kfull + k0 + lcol;
      __builtin_amdgcn_global_load_lds(
          (const __attribute__((address_space(1))) void*)gp,
          (__attribute__((address_space(3))) void*)(As + rbase * 32),
          16, 0, 0);
    }
    #pragma unroll
    for (int i = 0; i < TNB / 64; ++i) {
      const int rbase = i * 64 + wave * 16;
      const unsigned short* gp = Bw + (size_t)(rbase + lrow) * Kfull + k0 + lcol;
      __builtin_amdgcn_global_load_lds(
          (const __attribute__((address_space(1))) void*)gp,
          (__attribute__((address_space(3))) void*)(Bs + rbase * 32),
          16, 0, 0);
    }
    __syncthreads();

    bf16x8 af[4], bfr[NT];
    #pragma unroll
    for (int t = 0; t < 4; ++t)
      af[t]  = *reinterpret_cast<const bf16x8*>(As + (wm*64 + t*16 + fr)*32 + fq*8);
    #pragma unroll
    for (int t = 0; t < NT; ++t)
      bfr[t] = *reinterpret_cast<const bf16x8*>(Bs + (wn*WN + t*16 + fr)*32 + fq*8);
    #pragma unroll
    for (int mt = 0; mt < 4; ++mt)
      #pragma unroll
      for (int nt = 0; nt < NT; ++nt)
        acc[mt][nt] = __builtin_amdgcn_mfma_f32_16x16x32_bf16(
            af[mt], bfr[nt], acc[mt][nt], 0, 0, 0);
  }

  #pragma unroll
  for (int nt = 0; nt < NT; ++nt) {
    const int col = n0 + wn*WN + nt*16 + fr;
    #pragma unroll
    for (int mt = 0; mt < 4; ++mt)
      #pragma unroll
      for (int r = 0; r < 4; ++r) {
        const int row = m0 + wm*64 + mt*16 + fq*4 + r;
        Cw[(size_t)row * N + col] = f2bf(acc[mt][nt][r]);
      }
  }
}

// -------- split-K reduce: out = sum_z p[z] + bias + res (all bf16 in) ------
template<int SPLITS>
__global__ __launch_bounds__(256) void splitk_reduce(
    const unsigned short* __restrict__ p,   // [SPLITS][M*N] bf16
    const float* __restrict__ bias, const unsigned short* __restrict__ res,
    float* __restrict__ out)
{
  const size_t i = ((size_t)blockIdx.x * 256 + threadIdx.x) * 4;
  const size_t MN = (size_t)N_ROWS * C_;
  float4 bv = *reinterpret_cast<const float4*>(bias + (i & (size_t)(C_ - 1)));
  float acc[4] = {bv.x, bv.y, bv.z, bv.w};
  {
    const unsigned short* rp = res + i;
    #pragma unroll
    for (int j = 0; j < 4; ++j) acc[j] += bf2f(rp[j]);
  }
  #pragma unroll
  for (int z = 0; z < SPLITS; ++z) {
    const unsigned short* pp = p + (size_t)z * MN + i;
    #pragma unroll
    for (int j = 0; j < 4; ++j) acc[j] += bf2f(pp[j]);
  }
  float4 o; o.x = acc[0]; o.y = acc[1]; o.z = acc[2]; o.w = acc[3];
  *reinterpret_cast<float4*>(out + i) = o;
}

// ---------------- V transpose: qkv V-part -> vt[bh][64 d][2048 t] bf16 -----
__global__ __launch_bounds__(256) void v_transpose(
    const unsigned short* __restrict__ qkv, unsigned short* __restrict__ vt)
{
  __shared__ __align__(16) unsigned short sT[64][72];
  const int st = blockIdx.x;        // s-tile of 64
  const int bh = blockIdx.y;
  const int b = bh >> 4, h = bh & 15;
  const int t = threadIdx.x;
  const int r = t >> 2, c0 = (t & 3) * 16;
  const unsigned short* src =
      qkv + (size_t)(b * T_ + st * 64 + r) * 3072 + 2048 + h * 64 + c0;
  *(u16x8*)&sT[r][c0]     = *(const u16x8*)src;
  *(u16x8*)&sT[r][c0 + 8] = *(const u16x8*)(src + 8);
  __syncthreads();
  const int d = t >> 2, sc = (t & 3) * 16;
  unsigned short v[16];
  #pragma unroll
  for (int j = 0; j < 16; ++j) v[j] = sT[sc + j][d];
  unsigned short* dst = vt + ((size_t)bh * 64 + d) * (size_t)T_ + st * 64 + sc;
  *(uint4*)dst       = *(uint4*)&v[0];
  *(uint4*)(dst + 8) = *(uint4*)&v[8];
}

// ---------------- MFMA flash attention v2 (S^T form) ----------------
__global__ __launch_bounds__(256, 4) void attn_mfma(
    const unsigned short* __restrict__ qkv,
    const unsigned short* __restrict__ vt,
    unsigned short* __restrict__ out)
{
  const int bh = blockIdx.x;
  const int qt = (int)(gridDim.y - 1) - (int)blockIdx.y;  // long blocks first
  const int b = bh >> 4, h = bh & 15;
  const int tid = threadIdx.x;
  const int w = tid >> 6;
  const int lane = tid & 63;
  const int l15 = lane & 15, fq = lane >> 4;
  const int t0 = qt * 64;
  const int q_row = t0 + w * 16 + l15;   // this lane's q column

  __shared__ __align__(16) unsigned short sK [64][72];
  __shared__ __align__(16) unsigned short sVt[64][72];
  __shared__ __align__(16) unsigned short sP [64][72];

  // Q fragment (dual-use A/B layout): Q[q_row][d = c*32 + fq*8 + j]
  bf16x8 aq[2];
  {
    const unsigned short* qp = qkv + (size_t)(b*T_ + q_row)*3072 + h*HS_ + fq*8;
    aq[0] = *(const bf16x8*)qp;
    aq[1] = *(const bf16x8*)(qp + 32);
  }

  floatx4 oacc[4] = {};   // [dt]; C/D: col d = dt*16+l15, row q-local = fq*4+r
  float m_s = -3.0e38f, l_s = 0.0f;
  const float c1 = 1.4426950408889634f / 32.0f;   // log2(e) * C^-0.5
  const int nks = qt + 1;

  for (int ks = 0; ks < nks; ++ks) {
    __syncthreads();   // everyone done reading sK/sVt from previous iter
    {   // stage K tile [s][d] and Vt tile [d][s]
      const int r = tid >> 2, c0 = (tid & 3) * 16;
      const unsigned short* kp =
          qkv + (size_t)(b*T_ + ks*64 + r)*3072 + C_ + h*HS_ + c0;
      u16x8 k0 = *(const u16x8*)kp, k1 = *(const u16x8*)(kp + 8);
      const unsigned short* vp =
          vt + ((size_t)bh*64 + r)*(size_t)T_ + ks*64 + c0;
      u16x8 v0 = *(const u16x8*)vp, v1 = *(const u16x8*)(vp + 8);
      *(u16x8*)&sK[r][c0]      = k0; *(u16x8*)&sK[r][c0 + 8]  = k1;
      *(u16x8*)&sVt[r][c0]     = v0; *(u16x8*)&sVt[r][c0 + 8] = v1;
    }
    __syncthreads();

    // S^T[st] = K-tile · Q^T : D[m = s-local = fq*4+r][n = q-local = l15]
    floatx4 stacc[4] = {};
    #pragma unroll
    for (int st = 0; st < 4; ++st) {
      bf16x8 k0 = *(const bf16x8*)&sK[st*16 + l15][fq*8];
      bf16x8 k1 = *(const bf16x8*)&sK[st*16 + l15][32 + fq*8];
      stacc[st] = __builtin_amdgcn_mfma_f32_16x16x32_bf16(k0, aq[0], stacc[st], 0, 0, 0);
      stacc[st] = __builtin_amdgcn_mfma_f32_16x16x32_bf16(k1, aq[1], stacc[st], 0, 0, 0);
    }

    if (ks == qt) {   // diagonal tile: mask s > q
      #pragma unroll
      for (int st = 0; st < 4; ++st)
        #pragma unroll
        for (int r = 0; r < 4; ++r) {
          const int s = ks*64 + st*16 + fq*4 + r;
          if (s > q_row) stacc[st][r] = -3.0e38f;
        }
    }

    // online softmax over s for this lane's q: in-lane 16 + 2 shfl_xor
    float mx = -3.0e38f;
    #pragma unroll
    for (int st = 0; st < 4; ++st)
      #pragma unroll
      for (int r = 0; r < 4; ++r) mx = fmaxf(mx, stacc[st][r]);
    mx = fmaxf(mx, __shfl_xor(mx, 16, 64));
    mx = fmaxf(mx, __shfl_xor(mx, 32, 64));
    const float mnew = fmaxf(m_s, mx);
    const float alpha = exp2f((m_s - mnew) * c1);
    m_s = mnew;

    float sum = 0.0f;
    #pragma unroll
    for (int st = 0; st < 4; ++st) {
      unsigned pu[4];
      #pragma unroll
      for (int r = 0; r < 4; ++r) {
        const float p = exp2f((stacc[st][r] - mnew) * c1);
        sum += p;
        union { float f; unsigned u; } cv; cv.f = p;
        pu[r] = cv.u + 0x8000u;              // round-half-up to bf16
      }
      const unsigned lo = __builtin_amdgcn_perm(pu[1], pu[0], 0x07060302u);
      const unsigned hi = __builtin_amdgcn_perm(pu[3], pu[2], 0x07060302u);
      const unsigned long long pk = ((unsigned long long)hi << 32) | lo;
      // P[q][s]: row = wave-private q, col = 4 consecutive s
      *(unsigned long long*)&sP[w*16 + l15][st*16 + fq*4] = pk;
    }
    sum += __shfl_xor(sum, 16, 64);
    sum += __shfl_xor(sum, 32, 64);
    l_s = l_s * alpha + sum;

    // rescale O rows (alpha lives at lane l15 == q-local; O row = fq*4+r)
    #pragma unroll
    for (int r = 0; r < 4; ++r) {
      const float ar = __shfl(alpha, fq*4 + r, 64);
      #pragma unroll
      for (int dt = 0; dt < 4; ++dt) oacc[dt][r] *= ar;
    }

    // PV: O[q][d] += P[q][s] · V[s][d]   (sP rows are wave-private: no barrier)
    #pragma unroll
    for (int c = 0; c < 2; ++c) {
      bf16x8 ap = *(const bf16x8*)&sP[w*16 + l15][c*32 + fq*8];
      #pragma unroll
      for (int dt = 0; dt < 4; ++dt) {
        bf16x8 bv = *(const bf16x8*)&sVt[dt*16 + l15][c*32 + fq*8];
        oacc[dt] = __builtin_amdgcn_mfma_f32_16x16x32_bf16(ap, bv, oacc[dt], 0, 0, 0);
      }
    }
  }

  // epilogue: O /= l, write bf16 [token][h*64 + d]
  #pragma unroll
  for (int r = 0; r < 4; ++r) {
    const float il = 1.0f / __shfl(l_s, fq*4 + r, 64);
    const int q = t0 + w*16 + fq*4 + r;
    #pragma unroll
    for (int dt = 0; dt < 4; ++dt)
      out[(size_t)(b*T_ + q)*C_ + h*HS_ + dt*16 + l15] = f2bf(oacc[dt][r] * il);
  }
}

extern "C" void kernel_launch(void* const* d_in, const int* in_sizes, int n_in,
                              void* d_out, int out_size, void* d_ws, size_t ws_size,
                              hipStream_t stream)
{
  const float* x   = (const float*)d_in[0];
  const float* Wq  = (const float*)d_in[1];
  const float* Wk  = (const float*)d_in[2];
  const float* Wv  = (const float*)d_in[3];
  const float* Wo  = (const float*)d_in[4];
  const float* bo  = (const float*)d_in[5];
  const float* W1  = (const float*)d_in[6];
  const float* b1  = (const float*)d_in[7];
  const float* W2  = (const float*)d_in[8];
  const float* b2  = (const float*)d_in[9];
  const float* g1  = (const float*)d_in[10];
  const float* be1 = (const float*)d_in[11];
  const float* g2  = (const float*)d_in[12];
  const float* be2 = (const float*)d_in[13];
  float* out = (float*)d_out;

  // Workspace (96 MB peak, liveness-based reuse):
  char* ws = (char*)d_ws;
  unsigned short* BtQKV = (unsigned short*)(ws + (size_t) 0*MB);  // 6MB
  unsigned short* BtWo  = (unsigned short*)(ws + (size_t) 6*MB);  // 2MB
  unsigned short* BtW1  = (unsigned short*)(ws + (size_t) 8*MB);  // 8MB
  unsigned short* BtW2  = (unsigned short*)(ws + (size_t)16*MB);  // 8MB
  unsigned short* lnb   = (unsigned short*)(ws + (size_t)24*MB);  // 8MB
  unsigned short* qkvb  = (unsigned short*)(ws + (size_t)32*MB);  // [4096][3072] 24MB
  unsigned short* vtb   = (unsigned short*)(ws + (size_t)56*MB);  // [32][64][2048] 8MB
  unsigned short* attnb = (unsigned short*)(ws + (size_t)64*MB);  // 8MB
  float*          x2    = (float*)         (ws + (size_t)32*MB);  // 16MB (qkv dead)
  unsigned short* hb    = (unsigned short*)(ws + (size_t)32*MB);  // 32MB (x2,vt dead) -> 32-64
  // split-K bf16 partials for W2: [4][4096][1024] bf16 = 32 MB at 64-96 MB.
  // Live at that point: BtW2 (16-24), lnb (24-32), hb (32-64). vtb/attnb dead.
  unsigned short* pk4   = (unsigned short*)(ws + (size_t)64*MB);  // 32MB

  dim3 blk(256);

  // Weight transposes (QKV fused into one dispatch: z = which*16 + head)
  transpose_cast_qkv<<<dim3(HS_/32, C_/32, 3*H_), blk, 0, stream>>>(Wq, Wk, Wv, BtQKV);
  transpose_cast<<<dim3(C_/32,  C_/32, 1),  blk, 0, stream>>>(Wo, BtWo, C_, C_);
  transpose_cast<<<dim3(4*C_/32,C_/32, 1),  blk, 0, stream>>>(W1, BtW1, C_, 4*C_);
  transpose_cast<<<dim3(C_/32,4*C_/32, 1),  blk, 0, stream>>>(W2, BtW2, 4*C_, C_);

  ln_kernel<<<dim3(N_ROWS), blk, 0, stream>>>(x, g1, be1, lnb);

  // Fused QKV GEMM -> bf16 [4096][3072]   (768 blocks)
  gemm_bf16<128,true,false,false,false><<<dim3(N_ROWS/128, 3072/128), blk, 0, stream>>>(
      lnb, BtQKV, nullptr, nullptr, qkvb, N_ROWS, 3072, C_);

  // V transpose -> vt[bh][d][t]
  v_transpose<<<dim3(T_/64, B_*H_), blk, 0, stream>>>(qkvb, vtb);

  // MFMA flash attention -> bf16 attnb  (32 bh x 32 qt = 1024 blocks)
  attn_mfma<<<dim3(B_*H_, T_/64), blk, 0, stream>>>(qkvb, vtb, attnb);

  // Wo GEMM + bias + residual(ln1) -> fp32 x2   (TN=64: 512 blocks)
  gemm_bf16<64,false,false,true,true><<<dim3(N_ROWS/128, C_/64), blk, 0, stream>>>(
      attnb, BtWo, bo, lnb, x2, N_ROWS, C_, C_);

  // LN2
  ln_kernel<<<dim3(N_ROWS), blk, 0, stream>>>(x2, g2, be2, lnb);

  // W1 GEMM + bias + ReLU -> bf16 hb   (1024 blocks)
  gemm_bf16<128,true,true,true,false><<<dim3(N_ROWS/128, 4*C_/128), blk, 0, stream>>>(
      lnb, BtW1, b1, nullptr, hb, N_ROWS, 4*C_, C_);

  // W2 GEMM split-K=4 -> bf16 partials   (32 x 16 x 4 = 2048 blocks, K=1024 ea)
  gemm_splitk<64,4><<<dim3(N_ROWS/128, C_/64, 4), blk, 0, stream>>>(
      hb, BtW2, pk4, N_ROWS, C_, 4*C_);

  // reduce: out = sum(partials) + b2 + residual(ln2)
  splitk_reduce<4><<<dim3((N_ROWS * C_) / (256 * 4)), blk, 0, stream>>>(
      pk4, b2, lnb, out);
}

// Round 11
// 356.902 us; speedup vs baseline: 1.0806x; 1.0806x over previous
//
#include <hip/hip_runtime.h>
#include <hip/hip_bf16.h>
#include <math.h>

#define B_ 2
#define T_ 2048
#define C_ 1024
#define H_ 16
#define HS_ 64
#define N_ROWS (B_*T_)   // 4096
#define MB (1024*1024)

typedef __attribute__((ext_vector_type(8))) short bf16x8;
typedef __attribute__((ext_vector_type(8))) unsigned short u16x8;
typedef __attribute__((ext_vector_type(4))) float floatx4;

static __device__ __forceinline__ unsigned short f2bf(float f) {
  union { float f; unsigned u; } v; v.f = f;
  unsigned r = v.u + 0x7fff + ((v.u >> 16) & 1);   // round-to-nearest-even
  return (unsigned short)(r >> 16);
}
static __device__ __forceinline__ float bf2f(unsigned short s) {
  union { unsigned u; float f; } v; v.u = ((unsigned)s) << 16;
  return v.f;
}

// ---------------- LayerNorm: one block per row, bf16 output ----------------
__global__ __launch_bounds__(256) void ln_kernel(
    const float* __restrict__ x, const float* __restrict__ g,
    const float* __restrict__ b, unsigned short* __restrict__ outb)
{
  const int row = blockIdx.x;
  const int tid = threadIdx.x;
  const float* xr = x + (size_t)row * C_;
  float4 xv = *reinterpret_cast<const float4*>(xr + tid * 4);
  float s  = xv.x + xv.y + xv.z + xv.w;
  float ss = xv.x*xv.x + xv.y*xv.y + xv.z*xv.z + xv.w*xv.w;
  #pragma unroll
  for (int off = 32; off > 0; off >>= 1) {
    s  += __shfl_down(s, off, 64);
    ss += __shfl_down(ss, off, 64);
  }
  __shared__ float rs[4], rss[4];
  __shared__ float smu, srstd;
  if ((tid & 63) == 0) { rs[tid >> 6] = s; rss[tid >> 6] = ss; }
  __syncthreads();
  if (tid == 0) {
    float S  = rs[0] + rs[1] + rs[2] + rs[3];
    float SS = rss[0] + rss[1] + rss[2] + rss[3];
    float mu  = S * (1.0f / C_);
    float var = SS * (1.0f / C_) - mu * mu;
    smu = mu; srstd = rsqrtf(var + 1e-5f);
  }
  __syncthreads();
  const float mu = smu, rstd = srstd;
  float4 gv = *reinterpret_cast<const float4*>(g + tid * 4);
  float4 bv = *reinterpret_cast<const float4*>(b + tid * 4);
  union { unsigned long long ll; unsigned short s[4]; } o;
  o.s[0] = f2bf((xv.x - mu) * rstd * gv.x + bv.x);
  o.s[1] = f2bf((xv.y - mu) * rstd * gv.y + bv.y);
  o.s[2] = f2bf((xv.z - mu) * rstd * gv.z + bv.z);
  o.s[3] = f2bf((xv.w - mu) * rstd * gv.w + bv.w);
  *reinterpret_cast<unsigned long long*>(outb + (size_t)row * C_ + tid * 4) = o.ll;
}

// ---------------- Transpose + cast: fp32 [R][Cc] -> bf16 [Cc][R], batched ---
__global__ __launch_bounds__(256) void transpose_cast(
    const float* __restrict__ in, unsigned short* __restrict__ out, int R, int Cc)
{
  __shared__ float tile[32][33];
  const int bz = blockIdx.z;
  in  += (size_t)bz * R * Cc;
  out += (size_t)bz * R * Cc;
  const int tx = threadIdx.x & 31;
  const int ty = threadIdx.x >> 5;    // 0..7
  const int c0 = blockIdx.x * 32, r0 = blockIdx.y * 32;
  #pragma unroll
  for (int j = 0; j < 4; ++j)
    tile[ty + j*8][tx] = in[(size_t)(r0 + ty + j*8) * Cc + c0 + tx];
  __syncthreads();
  #pragma unroll
  for (int j = 0; j < 4; ++j)
    out[(size_t)(c0 + ty + j*8) * R + r0 + tx] = f2bf(tile[tx][ty + j*8]);
}

// Fused QKV weight transpose: z in [0,48) -> which = z/16, head = z%16.
__global__ __launch_bounds__(256) void transpose_cast_qkv(
    const float* __restrict__ Wq, const float* __restrict__ Wk,
    const float* __restrict__ Wv, unsigned short* __restrict__ out)
{
  __shared__ float tile[32][33];
  const int z = blockIdx.z;
  const int which = z >> 4, h = z & 15;
  const float* in = (which == 0 ? Wq : which == 1 ? Wk : Wv) + (size_t)h * C_ * HS_;
  unsigned short* dst = out + (size_t)z * C_ * HS_;
  const int tx = threadIdx.x & 31;
  const int ty = threadIdx.x >> 5;
  const int c0 = blockIdx.x * 32, r0 = blockIdx.y * 32;
  #pragma unroll
  for (int j = 0; j < 4; ++j)
    tile[ty + j*8][tx] = in[(size_t)(r0 + ty + j*8) * HS_ + c0 + tx];
  __syncthreads();
  #pragma unroll
  for (int j = 0; j < 4; ++j)
    dst[(size_t)(c0 + ty + j*8) * C_ + r0 + tx] = f2bf(tile[tx][ty + j*8]);
}

// ------------- bf16 MFMA GEMM, BK=64 via dual 32-wide panels --------------
// One barrier pair per 64-k: stage panels (k0, k0+32) into As[0/1]/Bs[0/1],
// then 2x16 MFMA per wave (TNB=128) before the next drain. Keeps the 64B-row
// LDS layout (global_load_lds is wave-uniform-base linear; padding illegal).
template<int TNB, bool OUTBF16, bool RELU, bool HASB, bool HASRES>
__global__ __launch_bounds__(256) void gemm_bf16(
    const unsigned short* __restrict__ A,   // [M][K] bf16
    const unsigned short* __restrict__ Bt,  // [N][K] bf16
    const float* __restrict__ bias,         // [N] fp32
    const unsigned short* __restrict__ res, // [M][N] bf16
    void* __restrict__ Cout,                // [M][N] fp32 or bf16
    int M, int N, int K)
{
  constexpr int NT = TNB / 32;              // B-tiles per wave: 4 or 2
  constexpr int WN = TNB / 2;               // wave n-extent: 64 or 32
  __shared__ unsigned short As[2][128 * 32];
  __shared__ unsigned short Bs[2][TNB * 32];
  const int tid  = threadIdx.x;
  const int lane = tid & 63;
  const int wave = tid >> 6;
  const int wm = wave & 1, wn = wave >> 1;
  const int m0 = blockIdx.x * 128, n0 = blockIdx.y * TNB;

  const int lrow = lane >> 2;
  const int lcol = (lane & 3) * 8;
  const int fr = lane & 15;
  const int fq = lane >> 4;

  floatx4 acc[4][NT] = {};

  const unsigned short* Aw = A  + (size_t)m0 * K;
  const unsigned short* Bw = Bt + (size_t)n0 * K;

  for (int k0 = 0; k0 < K; k0 += 64) {
    __syncthreads();
    #pragma unroll
    for (int half = 0; half < 2; ++half) {
      #pragma unroll
      for (int i = 0; i < 2; ++i) {
        const int rbase = i * 64 + wave * 16;
        const unsigned short* gp =
            Aw + (size_t)(rbase + lrow) * K + k0 + half * 32 + lcol;
        __builtin_amdgcn_global_load_lds(
            (const __attribute__((address_space(1))) void*)gp,
            (__attribute__((address_space(3))) void*)(As[half] + rbase * 32),
            16, 0, 0);
      }
      #pragma unroll
      for (int i = 0; i < TNB / 64; ++i) {
        const int rbase = i * 64 + wave * 16;
        const unsigned short* gp =
            Bw + (size_t)(rbase + lrow) * K + k0 + half * 32 + lcol;
        __builtin_amdgcn_global_load_lds(
            (const __attribute__((address_space(1))) void*)gp,
            (__attribute__((address_space(3))) void*)(Bs[half] + rbase * 32),
            16, 0, 0);
      }
    }
    __syncthreads();

    #pragma unroll
    for (int half = 0; half < 2; ++half) {
      bf16x8 af[4], bfr[NT];
      #pragma unroll
      for (int t = 0; t < 4; ++t)
        af[t]  = *reinterpret_cast<const bf16x8*>(
            As[half] + (wm*64 + t*16 + fr)*32 + fq*8);
      #pragma unroll
      for (int t = 0; t < NT; ++t)
        bfr[t] = *reinterpret_cast<const bf16x8*>(
            Bs[half] + (wn*WN + t*16 + fr)*32 + fq*8);
      #pragma unroll
      for (int mt = 0; mt < 4; ++mt)
        #pragma unroll
        for (int nt = 0; nt < NT; ++nt)
          acc[mt][nt] = __builtin_amdgcn_mfma_f32_16x16x32_bf16(
              af[mt], bfr[nt], acc[mt][nt], 0, 0, 0);
    }
  }

  #pragma unroll
  for (int nt = 0; nt < NT; ++nt) {
    const int col = n0 + wn*WN + nt*16 + fr;
    const float bv = HASB ? bias[col] : 0.0f;
    #pragma unroll
    for (int mt = 0; mt < 4; ++mt) {
      #pragma unroll
      for (int r = 0; r < 4; ++r) {
        const int row = m0 + wm*64 + mt*16 + fq*4 + r;
        float v = acc[mt][nt][r] + bv;
        if (RELU) v = v > 0.0f ? v : 0.0f;
        if (HASRES) v += bf2f(res[(size_t)row * N + col]);
        if (OUTBF16) ((unsigned short*)Cout)[(size_t)row * N + col] = f2bf(v);
        else         ((float*)Cout)[(size_t)row * N + col] = v;
      }
    }
  }
}

// ------- split-K (SPLITS-way) bf16 GEMM, BK=64 panels -> bf16 partials -----
template<int TNB, int SPLITS>
__global__ __launch_bounds__(256) void gemm_splitk(
    const unsigned short* __restrict__ A,   // [M][Kfull]
    const unsigned short* __restrict__ Bt,  // [N][Kfull]
    unsigned short* __restrict__ Cpart,     // [SPLITS][M][N] bf16
    int M, int N, int Kfull)
{
  constexpr int NT = TNB / 32;
  constexpr int WN = TNB / 2;
  __shared__ unsigned short As[2][128 * 32];
  __shared__ unsigned short Bs[2][TNB * 32];
  const int tid  = threadIdx.x;
  const int lane = tid & 63;
  const int wave = tid >> 6;
  const int wm = wave & 1, wn = wave >> 1;
  const int m0 = blockIdx.x * 128, n0 = blockIdx.y * TNB;
  const int z  = blockIdx.z;
  const int Kh = Kfull / SPLITS;

  const int lrow = lane >> 2;
  const int lcol = (lane & 3) * 8;
  const int fr = lane & 15;
  const int fq = lane >> 4;

  floatx4 acc[4][NT] = {};

  const unsigned short* Aw = A  + (size_t)m0 * Kfull + (size_t)z * Kh;
  const unsigned short* Bw = Bt + (size_t)n0 * Kfull + (size_t)z * Kh;
  unsigned short* Cw = Cpart + (size_t)z * M * N;

  for (int k0 = 0; k0 < Kh; k0 += 64) {
    __syncthreads();
    #pragma unroll
    for (int half = 0; half < 2; ++half) {
      #pragma unroll
      for (int i = 0; i < 2; ++i) {
        const int rbase = i * 64 + wave * 16;
        const unsigned short* gp =
            Aw + (size_t)(rbase + lrow) * Kfull + k0 + half * 32 + lcol;
        __builtin_amdgcn_global_load_lds(
            (const __attribute__((address_space(1))) void*)gp,
            (__attribute__((address_space(3))) void*)(As[half] + rbase * 32),
            16, 0, 0);
      }
      #pragma unroll
      for (int i = 0; i < TNB / 64; ++i) {
        const int rbase = i * 64 + wave * 16;
        const unsigned short* gp =
            Bw + (size_t)(rbase + lrow) * Kfull + k0 + half * 32 + lcol;
        __builtin_amdgcn_global_load_lds(
            (const __attribute__((address_space(1))) void*)gp,
            (__attribute__((address_space(3))) void*)(Bs[half] + rbase * 32),
            16, 0, 0);
      }
    }
    __syncthreads();

    #pragma unroll
    for (int half = 0; half < 2; ++half) {
      bf16x8 af[4], bfr[NT];
      #pragma unroll
      for (int t = 0; t < 4; ++t)
        af[t]  = *reinterpret_cast<const bf16x8*>(
            As[half] + (wm*64 + t*16 + fr)*32 + fq*8);
      #pragma unroll
      for (int t = 0; t < NT; ++t)
        bfr[t] = *reinterpret_cast<const bf16x8*>(
            Bs[half] + (wn*WN + t*16 + fr)*32 + fq*8);
      #pragma unroll
      for (int mt = 0; mt < 4; ++mt)
        #pragma unroll
        for (int nt = 0; nt < NT; ++nt)
          acc[mt][nt] = __builtin_amdgcn_mfma_f32_16x16x32_bf16(
              af[mt], bfr[nt], acc[mt][nt], 0, 0, 0);
    }
  }

  #pragma unroll
  for (int nt = 0; nt < NT; ++nt) {
    const int col = n0 + wn*WN + nt*16 + fr;
    #pragma unroll
    for (int mt = 0; mt < 4; ++mt)
      #pragma unroll
      for (int r = 0; r < 4; ++r) {
        const int row = m0 + wm*64 + mt*16 + fq*4 + r;
        Cw[(size_t)row * N + col] = f2bf(acc[mt][nt][r]);
      }
  }
}

// -------- split-K reduce: out = sum_z p[z] + bias + res (all bf16 in) ------
template<int SPLITS>
__global__ __launch_bounds__(256) void splitk_reduce(
    const unsigned short* __restrict__ p,   // [SPLITS][M*N] bf16
    const float* __restrict__ bias, const unsigned short* __restrict__ res,
    float* __restrict__ out)
{
  const size_t i = ((size_t)blockIdx.x * 256 + threadIdx.x) * 4;
  const size_t MN = (size_t)N_ROWS * C_;
  float4 bv = *reinterpret_cast<const float4*>(bias + (i & (size_t)(C_ - 1)));
  float acc[4] = {bv.x, bv.y, bv.z, bv.w};
  {
    const unsigned short* rp = res + i;
    #pragma unroll
    for (int j = 0; j < 4; ++j) acc[j] += bf2f(rp[j]);
  }
  #pragma unroll
  for (int z = 0; z < SPLITS; ++z) {
    const unsigned short* pp = p + (size_t)z * MN + i;
    #pragma unroll
    for (int j = 0; j < 4; ++j) acc[j] += bf2f(pp[j]);
  }
  float4 o; o.x = acc[0]; o.y = acc[1]; o.z = acc[2]; o.w = acc[3];
  *reinterpret_cast<float4*>(out + i) = o;
}

// ---------------- V transpose: qkv V-part -> vt[bh][64 d][2048 t] bf16 -----
__global__ __launch_bounds__(256) void v_transpose(
    const unsigned short* __restrict__ qkv, unsigned short* __restrict__ vt)
{
  __shared__ __align__(16) unsigned short sT[64][72];
  const int st = blockIdx.x;        // s-tile of 64
  const int bh = blockIdx.y;
  const int b = bh >> 4, h = bh & 15;
  const int t = threadIdx.x;
  const int r = t >> 2, c0 = (t & 3) * 16;
  const unsigned short* src =
      qkv + (size_t)(b * T_ + st * 64 + r) * 3072 + 2048 + h * 64 + c0;
  *(u16x8*)&sT[r][c0]     = *(const u16x8*)src;
  *(u16x8*)&sT[r][c0 + 8] = *(const u16x8*)(src + 8);
  __syncthreads();
  const int d = t >> 2, sc = (t & 3) * 16;
  unsigned short v[16];
  #pragma unroll
  for (int j = 0; j < 16; ++j) v[j] = sT[sc + j][d];
  unsigned short* dst = vt + ((size_t)bh * 64 + d) * (size_t)T_ + st * 64 + sc;
  *(uint4*)dst       = *(uint4*)&v[0];
  *(uint4*)(dst + 8) = *(uint4*)&v[8];
}

// ---------------- MFMA flash attention v2 (S^T form) ----------------
__global__ __launch_bounds__(256, 4) void attn_mfma(
    const unsigned short* __restrict__ qkv,
    const unsigned short* __restrict__ vt,
    unsigned short* __restrict__ out)
{
  const int bh = blockIdx.x;
  const int qt = (int)(gridDim.y - 1) - (int)blockIdx.y;  // long blocks first
  const int b = bh >> 4, h = bh & 15;
  const int tid = threadIdx.x;
  const int w = tid >> 6;
  const int lane = tid & 63;
  const int l15 = lane & 15, fq = lane >> 4;
  const int t0 = qt * 64;
  const int q_row = t0 + w * 16 + l15;   // this lane's q column

  __shared__ __align__(16) unsigned short sK [64][72];
  __shared__ __align__(16) unsigned short sVt[64][72];
  __shared__ __align__(16) unsigned short sP [64][72];

  // Q fragment (dual-use A/B layout): Q[q_row][d = c*32 + fq*8 + j]
  bf16x8 aq[2];
  {
    const unsigned short* qp = qkv + (size_t)(b*T_ + q_row)*3072 + h*HS_ + fq*8;
    aq[0] = *(const bf16x8*)qp;
    aq[1] = *(const bf16x8*)(qp + 32);
  }

  floatx4 oacc[4] = {};   // [dt]; C/D: col d = dt*16+l15, row q-local = fq*4+r
  float m_s = -3.0e38f, l_s = 0.0f;
  const float c1 = 1.4426950408889634f / 32.0f;   // log2(e) * C^-0.5
  const int nks = qt + 1;

  for (int ks = 0; ks < nks; ++ks) {
    __syncthreads();   // everyone done reading sK/sVt from previous iter
    {   // stage K tile [s][d] and Vt tile [d][s]
      const int r = tid >> 2, c0 = (tid & 3) * 16;
      const unsigned short* kp =
          qkv + (size_t)(b*T_ + ks*64 + r)*3072 + C_ + h*HS_ + c0;
      u16x8 k0 = *(const u16x8*)kp, k1 = *(const u16x8*)(kp + 8);
      const unsigned short* vp =
          vt + ((size_t)bh*64 + r)*(size_t)T_ + ks*64 + c0;
      u16x8 v0 = *(const u16x8*)vp, v1 = *(const u16x8*)(vp + 8);
      *(u16x8*)&sK[r][c0]      = k0; *(u16x8*)&sK[r][c0 + 8]  = k1;
      *(u16x8*)&sVt[r][c0]     = v0; *(u16x8*)&sVt[r][c0 + 8] = v1;
    }
    __syncthreads();

    // S^T[st] = K-tile · Q^T : D[m = s-local = fq*4+r][n = q-local = l15]
    floatx4 stacc[4] = {};
    #pragma unroll
    for (int st = 0; st < 4; ++st) {
      bf16x8 k0 = *(const bf16x8*)&sK[st*16 + l15][fq*8];
      bf16x8 k1 = *(const bf16x8*)&sK[st*16 + l15][32 + fq*8];
      stacc[st] = __builtin_amdgcn_mfma_f32_16x16x32_bf16(k0, aq[0], stacc[st], 0, 0, 0);
      stacc[st] = __builtin_amdgcn_mfma_f32_16x16x32_bf16(k1, aq[1], stacc[st], 0, 0, 0);
    }

    if (ks == qt) {   // diagonal tile: mask s > q
      #pragma unroll
      for (int st = 0; st < 4; ++st)
        #pragma unroll
        for (int r = 0; r < 4; ++r) {
          const int s = ks*64 + st*16 + fq*4 + r;
          if (s > q_row) stacc[st][r] = -3.0e38f;
        }
    }

    // online softmax over s for this lane's q: in-lane 16 + 2 shfl_xor
    float mx = -3.0e38f;
    #pragma unroll
    for (int st = 0; st < 4; ++st)
      #pragma unroll
      for (int r = 0; r < 4; ++r) mx = fmaxf(mx, stacc[st][r]);
    mx = fmaxf(mx, __shfl_xor(mx, 16, 64));
    mx = fmaxf(mx, __shfl_xor(mx, 32, 64));
    const float mnew = fmaxf(m_s, mx);
    const float alpha = exp2f((m_s - mnew) * c1);
    m_s = mnew;

    float sum = 0.0f;
    #pragma unroll
    for (int st = 0; st < 4; ++st) {
      unsigned pu[4];
      #pragma unroll
      for (int r = 0; r < 4; ++r) {
        const float p = exp2f((stacc[st][r] - mnew) * c1);
        sum += p;
        union { float f; unsigned u; } cv; cv.f = p;
        pu[r] = cv.u + 0x8000u;              // round-half-up to bf16
      }
      const unsigned lo = __builtin_amdgcn_perm(pu[1], pu[0], 0x07060302u);
      const unsigned hi = __builtin_amdgcn_perm(pu[3], pu[2], 0x07060302u);
      const unsigned long long pk = ((unsigned long long)hi << 32) | lo;
      // P[q][s]: row = wave-private q, col = 4 consecutive s
      *(unsigned long long*)&sP[w*16 + l15][st*16 + fq*4] = pk;
    }
    sum += __shfl_xor(sum, 16, 64);
    sum += __shfl_xor(sum, 32, 64);
    l_s = l_s * alpha + sum;

    // rescale O rows (alpha lives at lane l15 == q-local; O row = fq*4+r)
    #pragma unroll
    for (int r = 0; r < 4; ++r) {
      const float ar = __shfl(alpha, fq*4 + r, 64);
      #pragma unroll
      for (int dt = 0; dt < 4; ++dt) oacc[dt][r] *= ar;
    }

    // PV: O[q][d] += P[q][s] · V[s][d]   (sP rows are wave-private: no barrier)
    #pragma unroll
    for (int c = 0; c < 2; ++c) {
      bf16x8 ap = *(const bf16x8*)&sP[w*16 + l15][c*32 + fq*8];
      #pragma unroll
      for (int dt = 0; dt < 4; ++dt) {
        bf16x8 bv = *(const bf16x8*)&sVt[dt*16 + l15][c*32 + fq*8];
        oacc[dt] = __builtin_amdgcn_mfma_f32_16x16x32_bf16(ap, bv, oacc[dt], 0, 0, 0);
      }
    }
  }

  // epilogue: O /= l, write bf16 [token][h*64 + d]
  #pragma unroll
  for (int r = 0; r < 4; ++r) {
    const float il = 1.0f / __shfl(l_s, fq*4 + r, 64);
    const int q = t0 + w*16 + fq*4 + r;
    #pragma unroll
    for (int dt = 0; dt < 4; ++dt)
      out[(size_t)(b*T_ + q)*C_ + h*HS_ + dt*16 + l15] = f2bf(oacc[dt][r] * il);
  }
}

extern "C" void kernel_launch(void* const* d_in, const int* in_sizes, int n_in,
                              void* d_out, int out_size, void* d_ws, size_t ws_size,
                              hipStream_t stream)
{
  const float* x   = (const float*)d_in[0];
  const float* Wq  = (const float*)d_in[1];
  const float* Wk  = (const float*)d_in[2];
  const float* Wv  = (const float*)d_in[3];
  const float* Wo  = (const float*)d_in[4];
  const float* bo  = (const float*)d_in[5];
  const float* W1  = (const float*)d_in[6];
  const float* b1  = (const float*)d_in[7];
  const float* W2  = (const float*)d_in[8];
  const float* b2  = (const float*)d_in[9];
  const float* g1  = (const float*)d_in[10];
  const float* be1 = (const float*)d_in[11];
  const float* g2  = (const float*)d_in[12];
  const float* be2 = (const float*)d_in[13];
  float* out = (float*)d_out;

  // Workspace (96 MB peak, liveness-based reuse):
  char* ws = (char*)d_ws;
  unsigned short* BtQKV = (unsigned short*)(ws + (size_t) 0*MB);  // 6MB
  unsigned short* BtWo  = (unsigned short*)(ws + (size_t) 6*MB);  // 2MB
  unsigned short* BtW1  = (unsigned short*)(ws + (size_t) 8*MB);  // 8MB
  unsigned short* BtW2  = (unsigned short*)(ws + (size_t)16*MB);  // 8MB
  unsigned short* lnb   = (unsigned short*)(ws + (size_t)24*MB);  // 8MB
  unsigned short* qkvb  = (unsigned short*)(ws + (size_t)32*MB);  // [4096][3072] 24MB
  unsigned short* vtb   = (unsigned short*)(ws + (size_t)56*MB);  // [32][64][2048] 8MB
  unsigned short* attnb = (unsigned short*)(ws + (size_t)64*MB);  // 8MB
  float*          x2    = (float*)         (ws + (size_t)32*MB);  // 16MB (qkv dead)
  unsigned short* hb    = (unsigned short*)(ws + (size_t)32*MB);  // 32MB (x2,vt dead)
  // split-K bf16 partials for W2: [4][4096][1024] bf16 = 32 MB at 64-96 MB.
  unsigned short* pk4   = (unsigned short*)(ws + (size_t)64*MB);  // 32MB

  dim3 blk(256);

  // Weight transposes (QKV fused into one dispatch: z = which*16 + head)
  transpose_cast_qkv<<<dim3(HS_/32, C_/32, 3*H_), blk, 0, stream>>>(Wq, Wk, Wv, BtQKV);
  transpose_cast<<<dim3(C_/32,  C_/32, 1),  blk, 0, stream>>>(Wo, BtWo, C_, C_);
  transpose_cast<<<dim3(4*C_/32,C_/32, 1),  blk, 0, stream>>>(W1, BtW1, C_, 4*C_);
  transpose_cast<<<dim3(C_/32,4*C_/32, 1),  blk, 0, stream>>>(W2, BtW2, 4*C_, C_);

  ln_kernel<<<dim3(N_ROWS), blk, 0, stream>>>(x, g1, be1, lnb);

  // Fused QKV GEMM -> bf16 [4096][3072]   (768 blocks, BK=64 panels)
  gemm_bf16<128,true,false,false,false><<<dim3(N_ROWS/128, 3072/128), blk, 0, stream>>>(
      lnb, BtQKV, nullptr, nullptr, qkvb, N_ROWS, 3072, C_);

  // V transpose -> vt[bh][d][t]
  v_transpose<<<dim3(T_/64, B_*H_), blk, 0, stream>>>(qkvb, vtb);

  // MFMA flash attention -> bf16 attnb  (32 bh x 32 qt = 1024 blocks)
  attn_mfma<<<dim3(B_*H_, T_/64), blk, 0, stream>>>(qkvb, vtb, attnb);

  // Wo GEMM + bias + residual(ln1) -> fp32 x2   (TN=64: 512 blocks, control)
  gemm_bf16<64,false,false,true,true><<<dim3(N_ROWS/128, C_/64), blk, 0, stream>>>(
      attnb, BtWo, bo, lnb, x2, N_ROWS, C_, C_);

  // LN2
  ln_kernel<<<dim3(N_ROWS), blk, 0, stream>>>(x2, g2, be2, lnb);

  // W1 GEMM + bias + ReLU -> bf16 hb   (1024 blocks, BK=64 panels)
  gemm_bf16<128,true,true,true,false><<<dim3(N_ROWS/128, 4*C_/128), blk, 0, stream>>>(
      lnb, BtW1, b1, nullptr, hb, N_ROWS, 4*C_, C_);

  // W2 GEMM split-K=4, TNB=128, BK=64 -> bf16 partials (32 x 8 x 4 = 1024 blocks)
  gemm_splitk<128,4><<<dim3(N_ROWS/128, C_/128, 4), blk, 0, stream>>>(
      hb, BtW2, pk4, N_ROWS, C_, 4*C_);

  // reduce: out = sum(partials) + b2 + residual(ln2)
  splitk_reduce<4><<<dim3((N_ROWS * C_) / (256 * 4)), blk, 0, stream>>>(
      pk4, b2, lnb, out);
}